// Round 11
// baseline (265.790 us; speedup 1.0000x reference)
//
#include <hip/hip_runtime.h>
#include <stdint.h>

#define GAS __attribute__((address_space(1)))
#define LAS __attribute__((address_space(3)))

typedef __attribute__((ext_vector_type(8))) short short8;
typedef __attribute__((ext_vector_type(16))) float f32x16;
typedef __attribute__((ext_vector_type(4))) float f32x4;

static constexpr int N_TOK = 2048;
static constexpr int DM    = 1024;
static constexpr int DF    = 4096;
static constexpr int KP    = 4;

// ---------- helpers ----------
__device__ inline unsigned short f2bf(float f) {
  union { float f; uint32_t u; } v; v.f = f;
  uint32_t u = v.u;
  u += 0x7FFFu + ((u >> 16) & 1u);   // RNE
  return (unsigned short)(u >> 16);
}

__device__ inline uint32_t pk_bf(float lo, float hi) {
  union { float f; uint32_t u; } a, b; a.f = lo; b.f = hi;
  uint32_t ul = a.u + 0x7FFFu + ((a.u >> 16) & 1u);
  uint32_t uh = b.u + 0x7FFFu + ((b.u >> 16) & 1u);
  return (ul >> 16) | (uh & 0xFFFF0000u);
}

// gelu(v)*g, sigmoid form, overflow-safe
__device__ inline float gelu_gate(float v, float g) {
  float t0 = v * v;
  float u  = v * __builtin_fmaf(t0, -0.10294456f, -2.3022539f);
  float e  = __builtin_amdgcn_exp2f(u);
  float r  = __builtin_amdgcn_rcpf(1.0f + e);
  return v * g * r;
}

__device__ inline void gld16(const void* g, void* l) {
  __builtin_amdgcn_global_load_lds((const GAS void*)g, (LAS void*)l, 16, 0, 0);
}

// ---------- fused setup (rebalanced) ----------
__global__ __launch_bounds__(256) void setup_kernel(
    const float* __restrict__ tokens, const float* __restrict__ pb,
    const float* __restrict__ c11, const float* __restrict__ c12,
    const float* __restrict__ c21, const float* __restrict__ c22,
    float* __restrict__ gates, unsigned short* __restrict__ xb,
    unsigned short* __restrict__ w1t, unsigned short* __restrict__ w2t) {
  __shared__ __align__(16) float sh[17472];   // 69888 B
  const int blk = blockIdx.x;
  const int t = threadIdx.x;
  if (blk < 1024) {
    // ---- build_w1: w1t[k][f=x*64+y][d=a*32+b] ----
    const int k = blk >> 8, x = (blk >> 2) & 63, y0 = (blk & 3) * 16;
    float* s1  = sh;          // [a(32)][r(16)]
    float* s2T = sh + 512;    // [y(16)][stride 524], idx = r*32+b
    if (t < 128) {
      int a = t >> 2, rq = (t & 3) * 4;
      *(float4*)(s1 + a * 16 + rq) =
          *(const float4*)(c11 + (((size_t)(k * 32 + a)) * 64 + x) * 16 + rq);
    }
#pragma unroll
    for (int j = 0; j < 8; ++j) {
      int i = t + j * 256;              // [0,2048)
      int rb = i >> 2, yy0 = (i & 3) * 4;
      float4 v = *(const float4*)(c12 + (size_t)(k * 16) * 2048 + (size_t)rb * 64 + y0 + yy0);
      s2T[(yy0 + 0) * 524 + rb] = v.x;
      s2T[(yy0 + 1) * 524 + rb] = v.y;
      s2T[(yy0 + 2) * 524 + rb] = v.z;
      s2T[(yy0 + 3) * 524 + rb] = v.w;
    }
    __syncthreads();
    const int a = t >> 3, b0 = (t & 7) * 4;   // d = 4t (contiguous stores)
    float4 s1q[4];
#pragma unroll
    for (int q = 0; q < 4; ++q) s1q[q] = *(const float4*)(s1 + a * 16 + q * 4);
    const float* a0s = (const float*)s1q;
    for (int y = 0; y < 16; ++y) {
      const float* s2y = s2T + y * 524;
      float4 acc = {0.f, 0.f, 0.f, 0.f};
#pragma unroll
      for (int r = 0; r < 16; ++r) {
        float cv = a0s[r];
        float4 bv = *(const float4*)(s2y + r * 32 + b0);
        acc.x = __builtin_fmaf(cv, bv.x, acc.x);
        acc.y = __builtin_fmaf(cv, bv.y, acc.y);
        acc.z = __builtin_fmaf(cv, bv.z, acc.z);
        acc.w = __builtin_fmaf(cv, bv.w, acc.w);
      }
      ushort4 o; o.x = f2bf(acc.x); o.y = f2bf(acc.y); o.z = f2bf(acc.z); o.w = f2bf(acc.w);
      *(ushort4*)(w1t + ((size_t)k * DF + x * 64 + y0 + y) * DM + t * 4) = o;
    }
  } else if (blk < 2048) {
    // ---- build_w2: w2t[k][d=x*32+y][f=a*64+b], one jj per block ----
    const int bb = blk - 1024;
    const int jj = bb & 3;
    const int rest = bb >> 2;
    const int k = rest >> 6, x = (rest >> 1) & 31, y0 = (rest & 1) * 16;
    float* s1  = sh;           // [a(64)][r(16)]
    float* s2T = sh + 1024;    // [y(16)][stride 1028], idx = r*64+b
    {
      int a = t >> 2, rq = (t & 3) * 4;
      *(float4*)(s1 + a * 16 + rq) =
          *(const float4*)(c21 + (((size_t)(k * 64 + a)) * 32 + x) * 16 + rq);
    }
#pragma unroll
    for (int j = 0; j < 16; ++j) {
      int i = t + j * 256;              // [0,4096)
      int rb = i >> 2, yy0 = (i & 3) * 4;
      float4 v = *(const float4*)(c22 + (size_t)(k * 16) * 2048 + (size_t)rb * 32 + y0 + yy0);
      s2T[(yy0 + 0) * 1028 + rb] = v.x;
      s2T[(yy0 + 1) * 1028 + rb] = v.y;
      s2T[(yy0 + 2) * 1028 + rb] = v.z;
      s2T[(yy0 + 3) * 1028 + rb] = v.w;
    }
    __syncthreads();
    const int b0 = (t & 15) * 4;
    const int a = (t >> 4) + jj * 16;  // f = 4t + jj*1024
    float4 s1q[4];
#pragma unroll
    for (int q = 0; q < 4; ++q) s1q[q] = *(const float4*)(s1 + a * 16 + q * 4);
    const float* a0s = (const float*)s1q;
    for (int y = 0; y < 16; ++y) {
      const float* s2y = s2T + y * 1028;
      float4 acc = {0.f, 0.f, 0.f, 0.f};
#pragma unroll
      for (int r = 0; r < 16; ++r) {
        float cv = a0s[r];
        float4 bv = *(const float4*)(s2y + r * 64 + b0);
        acc.x = __builtin_fmaf(cv, bv.x, acc.x);
        acc.y = __builtin_fmaf(cv, bv.y, acc.y);
        acc.z = __builtin_fmaf(cv, bv.z, acc.z);
        acc.w = __builtin_fmaf(cv, bv.w, acc.w);
      }
      ushort4 o; o.x = f2bf(acc.x); o.y = f2bf(acc.y); o.z = f2bf(acc.z); o.w = f2bf(acc.w);
      *(ushort4*)(w2t + ((size_t)k * DM + x * 32 + y0 + y) * DF + t * 4 + jj * 1024) = o;
    }
  } else {
    // ---- prep: gates + bf16 cast ----
    const int wave = t >> 6, lane = t & 63;
    const int n = (blk - 2048) * 4 + wave;
    float s0 = 0.f, s1v = 0.f, s2v = 0.f, s3v = 0.f;
    const float4* tr = (const float4*)(tokens + (size_t)n * DM);
#pragma unroll
    for (int j = 0; j < 4; ++j) {
      int idx = j * 64 + lane;
      float4 tv = tr[idx];
      ushort4 b;
      b.x = f2bf(tv.x); b.y = f2bf(tv.y); b.z = f2bf(tv.z); b.w = f2bf(tv.w);
      *(ushort4*)(xb + (size_t)n * DM + idx * 4) = b;
      float4 q;
      q = ((const float4*)(pb + 0 * DM))[idx]; s0  += tv.x*q.x + tv.y*q.y + tv.z*q.z + tv.w*q.w;
      q = ((const float4*)(pb + 1 * DM))[idx]; s1v += tv.x*q.x + tv.y*q.y + tv.z*q.z + tv.w*q.w;
      q = ((const float4*)(pb + 2 * DM))[idx]; s2v += tv.x*q.x + tv.y*q.y + tv.z*q.z + tv.w*q.w;
      q = ((const float4*)(pb + 3 * DM))[idx]; s3v += tv.x*q.x + tv.y*q.y + tv.z*q.z + tv.w*q.w;
    }
#pragma unroll
    for (int off = 32; off > 0; off >>= 1) {
      s0  += __shfl_xor(s0, off);
      s1v += __shfl_xor(s1v, off);
      s2v += __shfl_xor(s2v, off);
      s3v += __shfl_xor(s3v, off);
    }
    if (lane == 0) {
      float m = fmaxf(fmaxf(s0, s1v), fmaxf(s2v, s3v));
      float e0 = __expf(s0 - m), e1 = __expf(s1v - m), e2 = __expf(s2v - m), e3 = __expf(s3v - m);
      float inv = 1.0f / (e0 + e1 + e2 + e3);
      float4 g; g.x = e0 * inv; g.y = e1 * inv; g.z = e2 * inv; g.w = e3 * inv;
      *(float4*)(gates + n * 4) = g;
    }
  }
}

// ---------- shared phase-sync (counted vmcnt + raw barrier) ----------
#define PH_SYNC(V) do { \
    asm volatile("s_waitcnt vmcnt(" #V ")" ::: "memory"); \
    __builtin_amdgcn_s_barrier(); \
    __builtin_amdgcn_sched_barrier(0); \
  } while (0)

// ---------- 128x128-tile 4-phase GEMM core (16x16x32 frags, 2 blocks/CU) ----
// 256 thr = 4 waves (wm 2 x wn 2), per-wave 64(A-dim) x 64(B-dim).
// QUADRANT-ALIGNED staging regions (R10 nan fix): each 32KB buffer =
//   W-lo: rows {0-31}@+0,     {64-95}@+4096   (the rA=0 rows of BOTH wm halves)
//   W-hi: rows {32-63}@+8192, {96-127}@+12288 (rA=1 rows)
//   X-lo: rows {0-31}@+16384, {64-95}@+20480  (cB=0)
//   X-hi: rows {32-63}@+24576,{96-127}@+28672 (cB=1)
// so phase p's vmcnt covers ALL waves' reads for that phase. dbuf = 64KB.
// Stage queue/tile: Wlo(2)@p0, Xlo(2)@p1, Xhi(2)@p2, Whi(2)@p3.
// vmcnt sim (8 loads in flight): steady (4,4,4) drains {Wlo,Xlo}/{Xhi}/{Whi}
// exactly before their reads; tail (4,2,0). Never 0 in main loop.
// Swizzle per 32-row 4KB sub-block: phys_chunk = logc ^ (r&7) ^ (r>>3);
// uniform lch staging, read chunk = (s*4) ^ cx ^ (fi*2).
#define MFMA8(ACCQ, AFR, BFR) do { \
  __builtin_amdgcn_s_setprio(1); \
  _Pragma("unroll") for (int fi = 0; fi < 2; ++fi) \
    _Pragma("unroll") for (int ti = 0; ti < 2; ++ti) { \
      ACCQ[fi][ti] = __builtin_amdgcn_mfma_f32_16x16x32_bf16(AFR[fi][0], BFR[ti][0], ACCQ[fi][ti], 0, 0, 0); \
      ACCQ[fi][ti] = __builtin_amdgcn_mfma_f32_16x16x32_bf16(AFR[fi][1], BFR[ti][1], ACCQ[fi][ti], 0, 0, 0); } \
  __builtin_amdgcn_s_setprio(0); \
} while (0)

#define GTILE(KT, BO, WO, V0, V1, V2, LIMIT, STR) do { \
  const int kn_ = ((KT) + 1) * 64; \
  const bool st_ = (KT) < (LIMIT); \
  /* p0 (0,0): read W-lo,X-lo frags; stage next W-lo */ \
  PH_SYNC(V0); \
  if (st_) { \
    gld16(Wg + (size_t)srow * (STR) + kn_ + lch * 8,        smem + (WO) + t * 16); \
    gld16(Wg + (size_t)(64 + srow) * (STR) + kn_ + lch * 8, smem + (WO) + 4096 + t * 16); } \
  _Pragma("unroll") for (int fi = 0; fi < 2; ++fi) \
    _Pragma("unroll") for (int s = 0; s < 2; ++s) \
      af[fi][s] = *(const short8*)(smem + (BO) + aB + fi * 2048 + (((s * 4) ^ cx ^ (fi * 2)) & 7) * 16); \
  _Pragma("unroll") for (int ti = 0; ti < 2; ++ti) \
    _Pragma("unroll") for (int s = 0; s < 2; ++s) \
      bf0[ti][s] = *(const short8*)(smem + (BO) + xB + ti * 2048 + (((s * 4) ^ cx ^ (ti * 2)) & 7) * 16); \
  MFMA8(acc[0][0], af, bf0); \
  /* p1 (0,1): read X-hi frags; stage next X-lo */ \
  PH_SYNC(V1); \
  if (st_) { \
    gld16(Xg + (size_t)srow * (STR) + kn_ + lch * 8,        smem + (WO) + 16384 + t * 16); \
    gld16(Xg + (size_t)(64 + srow) * (STR) + kn_ + lch * 8, smem + (WO) + 16384 + 4096 + t * 16); } \
  _Pragma("unroll") for (int ti = 0; ti < 2; ++ti) \
    _Pragma("unroll") for (int s = 0; s < 2; ++s) \
      bf1[ti][s] = *(const short8*)(smem + (BO) + xB + 8192 + ti * 2048 + (((s * 4) ^ cx ^ (ti * 2)) & 7) * 16); \
  MFMA8(acc[0][1], af, bf1); \
  /* p2 (1,1): read W-hi frags; stage next X-hi */ \
  PH_SYNC(V2); \
  if (st_) { \
    gld16(Xg + (size_t)(32 + srow) * (STR) + kn_ + lch * 8, smem + (WO) + 24576 + t * 16); \
    gld16(Xg + (size_t)(96 + srow) * (STR) + kn_ + lch * 8, smem + (WO) + 24576 + 4096 + t * 16); } \
  _Pragma("unroll") for (int fi = 0; fi < 2; ++fi) \
    _Pragma("unroll") for (int s = 0; s < 2; ++s) \
      af[fi][s] = *(const short8*)(smem + (BO) + aB + 8192 + fi * 2048 + (((s * 4) ^ cx ^ (fi * 2)) & 7) * 16); \
  MFMA8(acc[1][1], af, bf1); \
  /* p3 (1,0): no reads; stage next W-hi */ \
  if (st_) { \
    gld16(Wg + (size_t)(32 + srow) * (STR) + kn_ + lch * 8, smem + (WO) + 8192 + t * 16); \
    gld16(Wg + (size_t)(96 + srow) * (STR) + kn_ + lch * 8, smem + (WO) + 8192 + 4096 + t * 16); } \
  MFMA8(acc[1][0], af, bf0); \
} while (0)

// ---------- GEMM1: hg[k][n][f] = bf16(gelu(x@W1[k])*gate), 128x128 ----------
__global__ __launch_bounds__(256) void gemm1(
    const unsigned short* __restrict__ xb, const unsigned short* __restrict__ w1t,
    const float* __restrict__ gates, unsigned short* __restrict__ hg) {
  __shared__ __align__(16) char smem[65536];
  const int t = threadIdx.x, lane = t & 63, wv = t >> 6;
  const int wm = wv >> 1, wn = wv & 1;
  // T1 XCD swizzle (bijective, nwg=2048)
  const int hw = blockIdx.x + (blockIdx.y << 4) + (blockIdx.z << 9);
  const int lg = (hw & 7) * 256 + (hw >> 3);
  const int m0 = (lg & 15) * 128;          // token tile
  const int f0 = ((lg >> 4) & 31) * 128;   // f tile
  const int kp = lg >> 9;
  const unsigned short* __restrict__ Wg = w1t + (size_t)kp * DF * DM + (size_t)f0 * DM;
  const unsigned short* __restrict__ Xg = xb + (size_t)m0 * DM;

  const int srow = t >> 3;                       // [0,32) local row
  const int lch  = (t & 7) ^ (srow & 7) ^ (srow >> 3);
  const int l15 = lane & 15, kg = lane >> 4;
  const int cx  = kg ^ (l15 & 7) ^ (l15 >> 3);   // read chunk base
  const int aB  = wm * 4096 + l15 * 128;         // + rA*8192 + fi*2048
  const int xB  = 16384 + wn * 4096 + l15 * 128; // + cB*8192 + ti*2048

  f32x4 acc[2][2][2][2] = {};        // [rA][cB][fi][ti]
  short8 af[2][2], bf0[2][2], bf1[2][2];

  // prologue: stage tile 0, queue order Wlo, Xlo, Xhi, Whi
  {
    gld16(Wg + (size_t)srow * DM + lch * 8,        smem + t * 16);
    gld16(Wg + (size_t)(64 + srow) * DM + lch * 8, smem + 4096 + t * 16);
    gld16(Xg + (size_t)srow * DM + lch * 8,        smem + 16384 + t * 16);
    gld16(Xg + (size_t)(64 + srow) * DM + lch * 8, smem + 16384 + 4096 + t * 16);
    gld16(Xg + (size_t)(32 + srow) * DM + lch * 8, smem + 24576 + t * 16);
    gld16(Xg + (size_t)(96 + srow) * DM + lch * 8, smem + 24576 + 4096 + t * 16);
    gld16(Wg + (size_t)(32 + srow) * DM + lch * 8, smem + 8192 + t * 16);
    gld16(Wg + (size_t)(96 + srow) * DM + lch * 8, smem + 8192 + 4096 + t * 16);
  }

#pragma unroll 1
  for (int kt = 0; kt < 14; kt += 2) {
    GTILE(kt,     0,     32768, 4, 4, 4, 15, DM);
    GTILE(kt + 1, 32768, 0,     4, 4, 4, 15, DM);
  }
  GTILE(14, 0,     32768, 4, 4, 4, 15, DM);
  GTILE(15, 32768, 0,     4, 2, 0, 15, DM);   // tail: drain

  // epilogue: C col = tok (lane&15), row = f (kg*4 + reg)
  unsigned short* __restrict__ H = hg + (size_t)kp * N_TOK * DF;
#pragma unroll
  for (int cB = 0; cB < 2; ++cB)
#pragma unroll
    for (int ti = 0; ti < 2; ++ti) {
      const int tok = m0 + wn * 64 + cB * 32 + ti * 16 + l15;
      const float g = gates[tok * 4 + kp];
      unsigned short* hrow = H + (size_t)tok * DF + f0 + wm * 64 + kg * 4;
#pragma unroll
      for (int rA = 0; rA < 2; ++rA)
#pragma unroll
        for (int fi = 0; fi < 2; ++fi) {
          f32x4 v = acc[rA][cB][fi][ti];
          float r0 = gelu_gate(v.x, g);
          float r1 = gelu_gate(v.y, g);
          float r2 = gelu_gate(v.z, g);
          float r3 = gelu_gate(v.w, g);
          uint2 p; p.x = pk_bf(r0, r1); p.y = pk_bf(r2, r3);
          *(uint2*)(hrow + rA * 32 + fi * 16) = p;
        }
    }
}

// ---------- GEMM2: part[k][n][d] = (1+pw[k,d]) * (hg[k]@W2[k])[n,d], 128x128 --
__global__ __launch_bounds__(256) void gemm2(
    const unsigned short* __restrict__ hg, const unsigned short* __restrict__ w2t,
    const float* __restrict__ pw, float* __restrict__ part) {
  __shared__ __align__(16) char smem[65536];
  const int t = threadIdx.x, lane = t & 63, wv = t >> 6;
  const int wm = wv >> 1, wn = wv & 1;
  // T1 XCD swizzle (bijective, nwg=512)
  const int hw = blockIdx.x + (blockIdx.y << 4) + (blockIdx.z << 7);
  const int lg = (hw & 7) * 64 + (hw >> 3);
  const int m0 = (lg & 15) * 128;        // token tile
  const int n0 = ((lg >> 4) & 7) * 128;  // d tile
  const int kp = lg >> 7;
  const unsigned short* __restrict__ Wg = w2t + (size_t)kp * DM * DF + (size_t)n0 * DF;
  const unsigned short* __restrict__ Xg = hg + (size_t)kp * N_TOK * DF + (size_t)m0 * DF;

  const int srow = t >> 3;
  const int lch  = (t & 7) ^ (srow & 7) ^ (srow >> 3);
  const int l15 = lane & 15, kg = lane >> 4;
  const int cx  = kg ^ (l15 & 7) ^ (l15 >> 3);
  const int aB  = wm * 4096 + l15 * 128;
  const int xB  = 16384 + wn * 4096 + l15 * 128;

  f32x4 acc[2][2][2][2] = {};        // [rA][cB][fi][ti]
  short8 af[2][2], bf0[2][2], bf1[2][2];

  // prologue: stage tile 0, queue order Wlo, Xlo, Xhi, Whi
  {
    gld16(Wg + (size_t)srow * DF + lch * 8,        smem + t * 16);
    gld16(Wg + (size_t)(64 + srow) * DF + lch * 8, smem + 4096 + t * 16);
    gld16(Xg + (size_t)srow * DF + lch * 8,        smem + 16384 + t * 16);
    gld16(Xg + (size_t)(64 + srow) * DF + lch * 8, smem + 16384 + 4096 + t * 16);
    gld16(Xg + (size_t)(32 + srow) * DF + lch * 8, smem + 24576 + t * 16);
    gld16(Xg + (size_t)(96 + srow) * DF + lch * 8, smem + 24576 + 4096 + t * 16);
    gld16(Wg + (size_t)(32 + srow) * DF + lch * 8, smem + 8192 + t * 16);
    gld16(Wg + (size_t)(96 + srow) * DF + lch * 8, smem + 8192 + 4096 + t * 16);
  }

#pragma unroll 1
  for (int kt = 0; kt < 62; kt += 2) {
    GTILE(kt,     0,     32768, 4, 4, 4, 63, DF);
    GTILE(kt + 1, 32768, 0,     4, 4, 4, 63, DF);
  }
  GTILE(62, 0,     32768, 4, 4, 4, 63, DF);
  GTILE(63, 32768, 0,     4, 2, 0, 63, DF);   // tail: drain

  // epilogue: scale by (1+pw), float4 store
  float* __restrict__ P = part + (size_t)kp * N_TOK * DM;
  float4 pwv[2][2];   // [rA][fi]
#pragma unroll
  for (int rA = 0; rA < 2; ++rA)
#pragma unroll
    for (int fi = 0; fi < 2; ++fi) {
      float4 w = *(const float4*)(pw + kp * DM + n0 + wm * 64 + rA * 32 + fi * 16 + kg * 4);
      pwv[rA][fi].x = 1.0f + w.x; pwv[rA][fi].y = 1.0f + w.y;
      pwv[rA][fi].z = 1.0f + w.z; pwv[rA][fi].w = 1.0f + w.w;
    }
#pragma unroll
  for (int cB = 0; cB < 2; ++cB)
#pragma unroll
    for (int ti = 0; ti < 2; ++ti) {
      const int tok = m0 + wn * 64 + cB * 32 + ti * 16 + l15;
      float* prow = P + (size_t)tok * DM + n0 + wm * 64 + kg * 4;
#pragma unroll
      for (int rA = 0; rA < 2; ++rA)
#pragma unroll
        for (int fi = 0; fi < 2; ++fi) {
          f32x4 v = acc[rA][cB][fi][ti];
          float4 o;
          o.x = pwv[rA][fi].x * v.x;
          o.y = pwv[rA][fi].y * v.y;
          o.z = pwv[rA][fi].z * v.z;
          o.w = pwv[rA][fi].w * v.w;
          *(float4*)(prow + rA * 32 + fi * 16) = o;
        }
    }
}

// ---------- reduce partials over k ----------
__global__ __launch_bounds__(256) void reduce_k(
    const float* __restrict__ part, float* __restrict__ out) {
  const size_t i = ((size_t)blockIdx.x * 256 + threadIdx.x) * 4;
  const size_t S = (size_t)N_TOK * DM;
  float4 a = *(const float4*)(part + i);
  float4 b = *(const float4*)(part + S + i);
  float4 c = *(const float4*)(part + 2 * S + i);
  float4 d = *(const float4*)(part + 3 * S + i);
  float4 r;
  r.x = a.x + b.x + c.x + d.x;
  r.y = a.y + b.y + c.y + d.y;
  r.z = a.z + b.z + c.z + d.z;
  r.w = a.w + b.w + c.w + d.w;
  *(float4*)(out + i) = r;
}

// ---------- launcher ----------
extern "C" void kernel_launch(void* const* d_in, const int* in_sizes, int n_in,
                              void* d_out, int out_size, void* d_ws, size_t ws_size,
                              hipStream_t stream) {
  const float* tokens = (const float*)d_in[0];
  const float* f1c1   = (const float*)d_in[1];
  const float* f1c2   = (const float*)d_in[2];
  const float* f2c1   = (const float*)d_in[3];
  const float* f2c2   = (const float*)d_in[4];
  const float* pb     = (const float*)d_in[5];
  const float* pw     = (const float*)d_in[6];
  float* out = (float*)d_out;

  char* ws = (char*)d_ws;
  unsigned short* xb  = (unsigned short*)(ws);                  //   4 MB
  unsigned short* w1t = (unsigned short*)(ws + (4ull  << 20));  //  32 MB (dead after gemm1)
  float*          part = (float*)(ws + (4ull << 20));           //  32 MB (reuses w1t)
  unsigned short* w2t = (unsigned short*)(ws + (36ull << 20));  //  32 MB
  unsigned short* hg  = (unsigned short*)(ws + (68ull << 20));  //  64 MB
  float*          gates = (float*)(ws + (132ull << 20));        //  32 KB

  hipLaunchKernelGGL(setup_kernel, dim3(2560), dim3(256), 0, stream,
                     tokens, pb, f1c1, f1c2, f2c1, f2c2, gates, xb, w1t, w2t);
  hipLaunchKernelGGL(gemm1, dim3(16, 32, KP), dim3(256), 0, stream, xb, w1t, gates, hg);
  hipLaunchKernelGGL(gemm2, dim3(16, 8, KP), dim3(256), 0, stream, hg, w2t, pw, part);
  hipLaunchKernelGGL(reduce_k, dim3(2048), dim3(256), 0, stream, part, out);
}

// Round 14
// 249.532 us; speedup vs baseline: 1.0652x; 1.0652x over previous
//
#include <hip/hip_runtime.h>
#include <stdint.h>

#define GAS __attribute__((address_space(1)))
#define LAS __attribute__((address_space(3)))

typedef __attribute__((ext_vector_type(8))) short short8;
typedef __attribute__((ext_vector_type(16))) float f32x16;
typedef __attribute__((ext_vector_type(4))) float f32x4;

static constexpr int N_TOK = 2048;
static constexpr int DM    = 1024;
static constexpr int DF    = 4096;
static constexpr int KP    = 4;

// ---------- helpers ----------
__device__ inline unsigned short f2bf(float f) {
  union { float f; uint32_t u; } v; v.f = f;
  uint32_t u = v.u;
  u += 0x7FFFu + ((u >> 16) & 1u);   // RNE
  return (unsigned short)(u >> 16);
}

__device__ inline uint32_t pk_bf(float lo, float hi) {
  union { float f; uint32_t u; } a, b; a.f = lo; b.f = hi;
  uint32_t ul = a.u + 0x7FFFu + ((a.u >> 16) & 1u);
  uint32_t uh = b.u + 0x7FFFu + ((b.u >> 16) & 1u);
  return (ul >> 16) | (uh & 0xFFFF0000u);
}

// gelu(v)*g, sigmoid form, overflow-safe
__device__ inline float gelu_gate(float v, float g) {
  float t0 = v * v;
  float u  = v * __builtin_fmaf(t0, -0.10294456f, -2.3022539f);
  float e  = __builtin_amdgcn_exp2f(u);
  float r  = __builtin_amdgcn_rcpf(1.0f + e);
  return v * g * r;
}

__device__ inline void gld16(const void* g, void* l) {
  __builtin_amdgcn_global_load_lds((const GAS void*)g, (LAS void*)l, 16, 0, 0);
}

// ---------- fused setup (rebalanced; pw folded into w2t) ----------
// blocks [0,1024):     build_w1
// blocks [1024,2048):  build_w2 (jj hoisted into blockIdx; rows scaled by 1+pw)
// blocks [2048,2560):  prep (gates + bf16 cast)
__global__ __launch_bounds__(256) void setup_kernel(
    const float* __restrict__ tokens, const float* __restrict__ pb,
    const float* __restrict__ c11, const float* __restrict__ c12,
    const float* __restrict__ c21, const float* __restrict__ c22,
    const float* __restrict__ pw,
    float* __restrict__ gates, unsigned short* __restrict__ xb,
    unsigned short* __restrict__ w1t, unsigned short* __restrict__ w2t) {
  __shared__ __align__(16) float sh[17472];   // 69888 B
  const int blk = blockIdx.x;
  const int t = threadIdx.x;
  if (blk < 1024) {
    // ---- build_w1: w1t[k][f=x*64+y][d=a*32+b] ----
    const int k = blk >> 8, x = (blk >> 2) & 63, y0 = (blk & 3) * 16;
    float* s1  = sh;          // [a(32)][r(16)]
    float* s2T = sh + 512;    // [y(16)][stride 524], idx = r*32+b
    if (t < 128) {
      int a = t >> 2, rq = (t & 3) * 4;
      *(float4*)(s1 + a * 16 + rq) =
          *(const float4*)(c11 + (((size_t)(k * 32 + a)) * 64 + x) * 16 + rq);
    }
#pragma unroll
    for (int j = 0; j < 8; ++j) {
      int i = t + j * 256;              // [0,2048)
      int rb = i >> 2, yy0 = (i & 3) * 4;
      float4 v = *(const float4*)(c12 + (size_t)(k * 16) * 2048 + (size_t)rb * 64 + y0 + yy0);
      s2T[(yy0 + 0) * 524 + rb] = v.x;
      s2T[(yy0 + 1) * 524 + rb] = v.y;
      s2T[(yy0 + 2) * 524 + rb] = v.z;
      s2T[(yy0 + 3) * 524 + rb] = v.w;
    }
    __syncthreads();
    const int a = t >> 3, b0 = (t & 7) * 4;   // d = 4t (contiguous stores)
    float4 s1q[4];
#pragma unroll
    for (int q = 0; q < 4; ++q) s1q[q] = *(const float4*)(s1 + a * 16 + q * 4);
    const float* a0s = (const float*)s1q;
    for (int y = 0; y < 16; ++y) {
      const float* s2y = s2T + y * 524;
      float4 acc = {0.f, 0.f, 0.f, 0.f};
#pragma unroll
      for (int r = 0; r < 16; ++r) {
        float cv = a0s[r];
        float4 bv = *(const float4*)(s2y + r * 32 + b0);
        acc.x = __builtin_fmaf(cv, bv.x, acc.x);
        acc.y = __builtin_fmaf(cv, bv.y, acc.y);
        acc.z = __builtin_fmaf(cv, bv.z, acc.z);
        acc.w = __builtin_fmaf(cv, bv.w, acc.w);
      }
      ushort4 o; o.x = f2bf(acc.x); o.y = f2bf(acc.y); o.z = f2bf(acc.z); o.w = f2bf(acc.w);
      *(ushort4*)(w1t + ((size_t)k * DF + x * 64 + y0 + y) * DM + t * 4) = o;
    }
  } else if (blk < 2048) {
    // ---- build_w2: w2t[k][d=x*32+y][f=a*64+b] *(1+pw[k,d]), one jj per block --
    const int bb = blk - 1024;
    const int jj = bb & 3;
    const int rest = bb >> 2;
    const int k = rest >> 6, x = (rest >> 1) & 31, y0 = (rest & 1) * 16;
    float* s1  = sh;           // [a(64)][r(16)]
    float* s2T = sh + 1024;    // [y(16)][stride 1028], idx = r*64+b
    {
      int a = t >> 2, rq = (t & 3) * 4;
      *(float4*)(s1 + a * 16 + rq) =
          *(const float4*)(c21 + (((size_t)(k * 64 + a)) * 32 + x) * 16 + rq);
    }
#pragma unroll
    for (int j = 0; j < 16; ++j) {
      int i = t + j * 256;              // [0,4096)
      int rb = i >> 2, yy0 = (i & 3) * 4;
      float4 v = *(const float4*)(c22 + (size_t)(k * 16) * 2048 + (size_t)rb * 32 + y0 + yy0);
      s2T[(yy0 + 0) * 1028 + rb] = v.x;
      s2T[(yy0 + 1) * 1028 + rb] = v.y;
      s2T[(yy0 + 2) * 1028 + rb] = v.z;
      s2T[(yy0 + 3) * 1028 + rb] = v.w;
    }
    __syncthreads();
    const int b0 = (t & 15) * 4;
    const int a = (t >> 4) + jj * 16;  // f = 4t + jj*1024
    float4 s1q[4];
#pragma unroll
    for (int q = 0; q < 4; ++q) s1q[q] = *(const float4*)(s1 + a * 16 + q * 4);
    const float* a0s = (const float*)s1q;
    for (int y = 0; y < 16; ++y) {
      const float* s2y = s2T + y * 1028;
      const float scale = 1.0f + pw[k * DM + x * 32 + y0 + y];
      float4 acc = {0.f, 0.f, 0.f, 0.f};
#pragma unroll
      for (int r = 0; r < 16; ++r) {
        float cv = a0s[r];
        float4 bv = *(const float4*)(s2y + r * 64 + b0);
        acc.x = __builtin_fmaf(cv, bv.x, acc.x);
        acc.y = __builtin_fmaf(cv, bv.y, acc.y);
        acc.z = __builtin_fmaf(cv, bv.z, acc.z);
        acc.w = __builtin_fmaf(cv, bv.w, acc.w);
      }
      ushort4 o;
      o.x = f2bf(acc.x * scale); o.y = f2bf(acc.y * scale);
      o.z = f2bf(acc.z * scale); o.w = f2bf(acc.w * scale);
      *(ushort4*)(w2t + ((size_t)k * DM + x * 32 + y0 + y) * DF + t * 4 + jj * 1024) = o;
    }
  } else {
    // ---- prep: gates + bf16 cast ----
    const int wave = t >> 6, lane = t & 63;
    const int n = (blk - 2048) * 4 + wave;
    float s0 = 0.f, s1v = 0.f, s2v = 0.f, s3v = 0.f;
    const float4* tr = (const float4*)(tokens + (size_t)n * DM);
#pragma unroll
    for (int j = 0; j < 4; ++j) {
      int idx = j * 64 + lane;
      float4 tv = tr[idx];
      ushort4 b;
      b.x = f2bf(tv.x); b.y = f2bf(tv.y); b.z = f2bf(tv.z); b.w = f2bf(tv.w);
      *(ushort4*)(xb + (size_t)n * DM + idx * 4) = b;
      float4 q;
      q = ((const float4*)(pb + 0 * DM))[idx]; s0  += tv.x*q.x + tv.y*q.y + tv.z*q.z + tv.w*q.w;
      q = ((const float4*)(pb + 1 * DM))[idx]; s1v += tv.x*q.x + tv.y*q.y + tv.z*q.z + tv.w*q.w;
      q = ((const float4*)(pb + 2 * DM))[idx]; s2v += tv.x*q.x + tv.y*q.y + tv.z*q.z + tv.w*q.w;
      q = ((const float4*)(pb + 3 * DM))[idx]; s3v += tv.x*q.x + tv.y*q.y + tv.z*q.z + tv.w*q.w;
    }
#pragma unroll
    for (int off = 32; off > 0; off >>= 1) {
      s0  += __shfl_xor(s0, off);
      s1v += __shfl_xor(s1v, off);
      s2v += __shfl_xor(s2v, off);
      s3v += __shfl_xor(s3v, off);
    }
    if (lane == 0) {
      float m = fmaxf(fmaxf(s0, s1v), fmaxf(s2v, s3v));
      float e0 = __expf(s0 - m), e1 = __expf(s1v - m), e2 = __expf(s2v - m), e3 = __expf(s3v - m);
      float inv = 1.0f / (e0 + e1 + e2 + e3);
      float4 g; g.x = e0 * inv; g.y = e1 * inv; g.z = e2 * inv; g.w = e3 * inv;
      *(float4*)(gates + n * 4) = g;
    }
  }
}

// ---------- shared phase-sync (counted vmcnt + raw barrier) ----------
#define PH_SYNC(V) do { \
    asm volatile("s_waitcnt vmcnt(" #V ")" ::: "memory"); \
    __builtin_amdgcn_s_barrier(); \
    __builtin_amdgcn_sched_barrier(0); \
  } while (0)

// ---------- GEMM1 (R3 best: 4-phase 256x256, counted vmcnt) ----------
// hg[k][n][f] = bf16(gelu(x@W1[k])*gate)
#define G1_TILE(KT, BO, WO, V0, V1, V2) do { \
    const int kn_ = ((KT) + 1) * 64; \
    const bool st_ = (KT) < 15; \
    /* ---- phase 0: quadrant (rA=0,cB=0); reads W0,X0; stages next W0 ---- */ \
    PH_SYNC(V0); \
    if (st_) { const unsigned short* s_ = Wg + (size_t)srow * DM + kn_ + lch * 8; \
      gld16(s_, smem + (WO) + t * 16); gld16(s_ + 64 * DM, smem + (WO) + 8192 + t * 16); } \
    _Pragma("unroll") for (int fi = 0; fi < 4; ++fi) \
      _Pragma("unroll") for (int s = 0; s < 2; ++s) \
        af[fi][s] = *(const short8*)(smem + (BO) + aRowB + fi * 2048 + (cxor16 ^ (s * 64) ^ (fi * 32))); \
    _Pragma("unroll") for (int ti = 0; ti < 2; ++ti) \
      _Pragma("unroll") for (int s = 0; s < 2; ++s) \
        bf0[ti][s] = *(const short8*)(smem + (BO) + xRowB + ti * 2048 + (cxor16 ^ (s * 64) ^ wnx64 ^ (ti * 32))); \
    __builtin_amdgcn_s_setprio(1); \
    _Pragma("unroll") for (int fi = 0; fi < 4; ++fi) \
      _Pragma("unroll") for (int ti = 0; ti < 2; ++ti) { \
        acc[0][0][fi][ti] = __builtin_amdgcn_mfma_f32_16x16x32_bf16(af[fi][0], bf0[ti][0], acc[0][0][fi][ti], 0, 0, 0); \
        acc[0][0][fi][ti] = __builtin_amdgcn_mfma_f32_16x16x32_bf16(af[fi][1], bf0[ti][1], acc[0][0][fi][ti], 0, 0, 0); } \
    __builtin_amdgcn_s_setprio(0); \
    /* ---- phase 1: quadrant (rA=0,cB=1); reads X1; stages next X0 ---- */ \
    PH_SYNC(V1); \
    if (st_) { const unsigned short* s_ = Xg + (size_t)srow * DM + kn_ + lch * 8; \
      gld16(s_, smem + (WO) + 32768 + t * 16); gld16(s_ + 64 * DM, smem + (WO) + 32768 + 8192 + t * 16); } \
    _Pragma("unroll") for (int ti = 0; ti < 2; ++ti) \
      _Pragma("unroll") for (int s = 0; s < 2; ++s) \
        bf1[ti][s] = *(const short8*)(smem + (BO) + xRowB + 16384 + ti * 2048 + (cxor16 ^ (s * 64) ^ wnx64 ^ (ti * 32))); \
    __builtin_amdgcn_s_setprio(1); \
    _Pragma("unroll") for (int fi = 0; fi < 4; ++fi) \
      _Pragma("unroll") for (int ti = 0; ti < 2; ++ti) { \
        acc[0][1][fi][ti] = __builtin_amdgcn_mfma_f32_16x16x32_bf16(af[fi][0], bf1[ti][0], acc[0][1][fi][ti], 0, 0, 0); \
        acc[0][1][fi][ti] = __builtin_amdgcn_mfma_f32_16x16x32_bf16(af[fi][1], bf1[ti][1], acc[0][1][fi][ti], 0, 0, 0); } \
    __builtin_amdgcn_s_setprio(0); \
    /* ---- phase 2: quadrant (rA=1,cB=1); reads W1; stages next X1 ---- */ \
    PH_SYNC(V2); \
    if (st_) { const unsigned short* s_ = Xg + (size_t)(128 + srow) * DM + kn_ + lch * 8; \
      gld16(s_, smem + (WO) + 32768 + 16384 + t * 16); gld16(s_ + 64 * DM, smem + (WO) + 32768 + 16384 + 8192 + t * 16); } \
    _Pragma("unroll") for (int fi = 0; fi < 4; ++fi) \
      _Pragma("unroll") for (int s = 0; s < 2; ++s) \
        af[fi][s] = *(const short8*)(smem + (BO) + aRowB + 16384 + fi * 2048 + (cxor16 ^ (s * 64) ^ (fi * 32))); \
    __builtin_amdgcn_s_setprio(1); \
    _Pragma("unroll") for (int fi = 0; fi < 4; ++fi) \
      _Pragma("unroll") for (int ti = 0; ti < 2; ++ti) { \
        acc[1][1][fi][ti] = __builtin_amdgcn_mfma_f32_16x16x32_bf16(af[fi][0], bf1[ti][0], acc[1][1][fi][ti], 0, 0, 0); \
        acc[1][1][fi][ti] = __builtin_amdgcn_mfma_f32_16x16x32_bf16(af[fi][1], bf1[ti][1], acc[1][1][fi][ti], 0, 0, 0); } \
    __builtin_amdgcn_s_setprio(0); \
    /* ---- phase 3: quadrant (rA=1,cB=0); no new reads; stages next W1 ---- */ \
    if (st_) { const unsigned short* s_ = Wg + (size_t)(128 + srow) * DM + kn_ + lch * 8; \
      gld16(s_, smem + (WO) + 16384 + t * 16); gld16(s_ + 64 * DM, smem + (WO) + 16384 + 8192 + t * 16); } \
    __builtin_amdgcn_s_setprio(1); \
    _Pragma("unroll") for (int fi = 0; fi < 4; ++fi) \
      _Pragma("unroll") for (int ti = 0; ti < 2; ++ti) { \
        acc[1][0][fi][ti] = __builtin_amdgcn_mfma_f32_16x16x32_bf16(af[fi][0], bf0[ti][0], acc[1][0][fi][ti], 0, 0, 0); \
        acc[1][0][fi][ti] = __builtin_amdgcn_mfma_f32_16x16x32_bf16(af[fi][1], bf0[ti][1], acc[1][0][fi][ti], 0, 0, 0); } \
    __builtin_amdgcn_s_setprio(0); \
  } while (0)

__global__ __launch_bounds__(512, 1) void gemm1(
    const unsigned short* __restrict__ xb, const unsigned short* __restrict__ w1t,
    const float* __restrict__ gates, unsigned short* __restrict__ hg) {
  __shared__ __align__(16) char smem[131072];
  const int t = threadIdx.x, lane = t & 63, wv = t >> 6;
  const int wm = wv >> 2, wn = wv & 3;
  // T1 XCD swizzle (bijective, nwg=512)
  const int hw = blockIdx.x + (blockIdx.y << 3) + (blockIdx.z << 7);
  const int lg = (hw & 7) * 64 + (hw >> 3);
  const int m0 = (lg & 7) * 256;          // token tile
  const int f0 = ((lg >> 3) & 15) * 256;  // f tile
  const int kp = lg >> 7;
  const unsigned short* __restrict__ Wg = w1t + (size_t)kp * DF * DM + (size_t)f0 * DM;
  const unsigned short* __restrict__ Xg = xb + (size_t)m0 * DM;

  const int srow = t >> 3;
  const int lch  = (t & 7) ^ (srow & 7) ^ (srow >> 3);
  const int l15 = lane & 15, kg = lane >> 4;
  const int cxor16 = (kg ^ (lane & 7) ^ (l15 >> 3)) * 16;  // bytes
  const int wnx64  = (wn & 1) * 64;
  const int aRowB  = (wm * 64 + l15) * 128;                // W rows, + rA*16384 + fi*2048
  const int xRowB  = 32768 + (wn * 32 + l15) * 128;        // X rows, + cB*16384 + ti*2048

  f32x4 acc[2][2][4][2] = {};        // [rA][cB][fi][ti]
  short8 af[4][2], bf0[2][2], bf1[2][2];

  // prologue: stage tile 0 (queue order W0, X0, X1, W1)
  {
    const unsigned short* sw = Wg + (size_t)srow * DM + lch * 8;
    const unsigned short* sx = Xg + (size_t)srow * DM + lch * 8;
    gld16(sw,            smem + t * 16);
    gld16(sw + 64 * DM,  smem + 8192 + t * 16);
    gld16(sx,            smem + 32768 + t * 16);
    gld16(sx + 64 * DM,  smem + 32768 + 8192 + t * 16);
    gld16(sx + 128 * DM, smem + 32768 + 16384 + t * 16);
    gld16(sx + 192 * DM, smem + 32768 + 16384 + 8192 + t * 16);
    gld16(sw + 128 * DM, smem + 16384 + t * 16);
    gld16(sw + 192 * DM, smem + 16384 + 8192 + t * 16);
  }

#pragma unroll 1
  for (int kt = 0; kt < 14; kt += 2) {
    G1_TILE(kt,     0,     65536, 4, 4, 4);
    G1_TILE(kt + 1, 65536, 0,     4, 4, 4);
  }
  G1_TILE(14, 0,     65536, 4, 4, 4);
  G1_TILE(15, 65536, 0,     4, 2, 0);   // tail: drain (no stages issued)

  // epilogue: C row = f (lane>>4)*4+reg, col = token (lane&15)
  unsigned short* __restrict__ H = hg + (size_t)kp * N_TOK * DF;
#pragma unroll
  for (int cB = 0; cB < 2; ++cB)
#pragma unroll
    for (int ti = 0; ti < 2; ++ti) {
      const int tok = m0 + cB * 128 + wn * 32 + ti * 16 + l15;
      const float g = gates[tok * 4 + kp];
      unsigned short* hrow = H + (size_t)tok * DF + f0 + wm * 64 + kg * 4;
#pragma unroll
      for (int rA = 0; rA < 2; ++rA)
#pragma unroll
        for (int fi = 0; fi < 4; ++fi) {
          f32x4 v = acc[rA][cB][fi][ti];
          float r0 = gelu_gate(v.x, g);
          float r1 = gelu_gate(v.y, g);
          float r2 = gelu_gate(v.z, g);
          float r3 = gelu_gate(v.w, g);
          uint2 p; p.x = pk_bf(r0, r1); p.y = pk_bf(r2, r3);
          *(uint2*)(hrow + rA * 128 + fi * 16) = p;
        }
    }
}

// ---------- GEMM2 (R3 best: counted-vmcnt 4-phase, 256tok x 128d) ----------
// part[k][n][d] = (hg[k] @ w2t_scaled[k])[n,d]   (pw pre-folded into w2t)
#define G2_TILE(KT, BO, WO, V0, V1, V2) do { \
    const int kn_ = ((KT) + 1) * 64; \
    const bool st_ = (KT) < 63; \
    /* ---- phase 0: (rA=0,cB=0); reads WH0,XH0; stages next WH0 ---- */ \
    PH_SYNC(V0); \
    if (st_) gld16(Wg + (size_t)srow * DF + kn_ + lch * 8, smem + (WO) + t * 16); \
    _Pragma("unroll") for (int fi = 0; fi < 2; ++fi) \
      _Pragma("unroll") for (int s = 0; s < 2; ++s) \
        af[fi][s] = *(const short8*)(smem + (BO) + awRowB + fi * 2048 + (cxor16 ^ awx ^ (fi * 32) ^ (s * 64))); \
    _Pragma("unroll") for (int ti = 0; ti < 2; ++ti) \
      _Pragma("unroll") for (int s = 0; s < 2; ++s) \
        bf0[ti][s] = *(const short8*)(smem + (BO) + xRowB + ti * 2048 + (cxor16 ^ wnx64 ^ (ti * 32) ^ (s * 64))); \
    __builtin_amdgcn_s_setprio(1); \
    _Pragma("unroll") for (int fi = 0; fi < 2; ++fi) \
      _Pragma("unroll") for (int ti = 0; ti < 2; ++ti) { \
        acc[0][0][fi][ti] = __builtin_amdgcn_mfma_f32_16x16x32_bf16(af[fi][0], bf0[ti][0], acc[0][0][fi][ti], 0, 0, 0); \
        acc[0][0][fi][ti] = __builtin_amdgcn_mfma_f32_16x16x32_bf16(af[fi][1], bf0[ti][1], acc[0][0][fi][ti], 0, 0, 0); } \
    __builtin_amdgcn_s_setprio(0); \
    /* ---- phase 1: (rA=0,cB=1); reads XH1; stages next XH0 ---- */ \
    PH_SYNC(V1); \
    if (st_) { const unsigned short* s_ = Xg + (size_t)srow * DF + kn_ + lch * 8; \
      gld16(s_, smem + (WO) + 16384 + t * 16); gld16(s_ + 64 * DF, smem + (WO) + 16384 + 8192 + t * 16); } \
    _Pragma("unroll") for (int ti = 0; ti < 2; ++ti) \
      _Pragma("unroll") for (int s = 0; s < 2; ++s) \
        bf1[ti][s] = *(const short8*)(smem + (BO) + xRowB + 16384 + ti * 2048 + (cxor16 ^ wnx64 ^ (ti * 32) ^ (s * 64))); \
    __builtin_amdgcn_s_setprio(1); \
    _Pragma("unroll") for (int fi = 0; fi < 2; ++fi) \
      _Pragma("unroll") for (int ti = 0; ti < 2; ++ti) { \
        acc[0][1][fi][ti] = __builtin_amdgcn_mfma_f32_16x16x32_bf16(af[fi][0], bf1[ti][0], acc[0][1][fi][ti], 0, 0, 0); \
        acc[0][1][fi][ti] = __builtin_amdgcn_mfma_f32_16x16x32_bf16(af[fi][1], bf1[ti][1], acc[0][1][fi][ti], 0, 0, 0); } \
    __builtin_amdgcn_s_setprio(0); \
    /* ---- phase 2: (rA=1,cB=1); reads WH1; stages next XH1 ---- */ \
    PH_SYNC(V2); \
    if (st_) { const unsigned short* s_ = Xg + (size_t)(128 + srow) * DF + kn_ + lch * 8; \
      gld16(s_, smem + (WO) + 32768 + t * 16); gld16(s_ + 64 * DF, smem + (WO) + 32768 + 8192 + t * 16); } \
    _Pragma("unroll") for (int fi = 0; fi < 2; ++fi) \
      _Pragma("unroll") for (int s = 0; s < 2; ++s) \
        af[fi][s] = *(const short8*)(smem + (BO) + awRowB + 8192 + fi * 2048 + (cxor16 ^ awx ^ (fi * 32) ^ (s * 64))); \
    __builtin_amdgcn_s_setprio(1); \
    _Pragma("unroll") for (int fi = 0; fi < 2; ++fi) \
      _Pragma("unroll") for (int ti = 0; ti < 2; ++ti) { \
        acc[1][1][fi][ti] = __builtin_amdgcn_mfma_f32_16x16x32_bf16(af[fi][0], bf1[ti][0], acc[1][1][fi][ti], 0, 0, 0); \
        acc[1][1][fi][ti] = __builtin_amdgcn_mfma_f32_16x16x32_bf16(af[fi][1], bf1[ti][1], acc[1][1][fi][ti], 0, 0, 0); } \
    __builtin_amdgcn_s_setprio(0); \
    /* ---- phase 3: (rA=1,cB=0); register-only; stages next WH1 ---- */ \
    if (st_) gld16(Wg + (size_t)(64 + srow) * DF + kn_ + lch * 8, smem + (WO) + 8192 + t * 16); \
    __builtin_amdgcn_s_setprio(1); \
    _Pragma("unroll") for (int fi = 0; fi < 2; ++fi) \
      _Pragma("unroll") for (int ti = 0; ti < 2; ++ti) { \
        acc[1][0][fi][ti] = __builtin_amdgcn_mfma_f32_16x16x32_bf16(af[fi][0], bf0[ti][0], acc[1][0][fi][ti], 0, 0, 0); \
        acc[1][0][fi][ti] = __builtin_amdgcn_mfma_f32_16x16x32_bf16(af[fi][1], bf0[ti][1], acc[1][0][fi][ti], 0, 0, 0); } \
    __builtin_amdgcn_s_setprio(0); \
  } while (0)

__global__ __launch_bounds__(512, 1) void gemm2(
    const unsigned short* __restrict__ hg, const unsigned short* __restrict__ w2t,
    float* __restrict__ part) {
  __shared__ __align__(16) char smem[98304];
  const int t = threadIdx.x, lane = t & 63, wv = t >> 6;
  const int wm = wv >> 2, wn = wv & 3;
  // T1 XCD swizzle (bijective, nwg=256)
  const int hw = blockIdx.x + (blockIdx.y << 3) + (blockIdx.z << 6);
  const int lg = (hw & 7) * 32 + (hw >> 3);
  const int m0 = (lg & 7) * 256;         // token tile
  const int n0 = ((lg >> 3) & 7) * 128;  // d tile
  const int kp = lg >> 6;
  const unsigned short* __restrict__ Wg = w2t + (size_t)kp * DM * DF + (size_t)n0 * DF;
  const unsigned short* __restrict__ Xg = hg + (size_t)kp * N_TOK * DF + (size_t)m0 * DF;

  const int srow = t >> 3;
  const int lch  = (t & 7) ^ (srow & 7) ^ (srow >> 3);
  const int l15 = lane & 15, kg = lane >> 4;
  const int cxor16 = (kg ^ (lane & 7) ^ (l15 >> 3)) * 16;  // bytes
  const int wnx64  = (wn & 1) * 64;
  const int awx    = wm * 64;                               // (wm*4)*16 bytes
  const int awRowB = (wm * 32 + l15) * 128;                 // W rows, + rA*8192 + fi*2048
  const int xRowB  = 16384 + (wn * 32 + l15) * 128;         // X rows, + cB*16384 + ti*2048

  f32x4 acc[2][2][2][2] = {};        // [rA][cB][fi][ti]
  short8 af[2][2], bf0[2][2], bf1[2][2];

  // prologue: stage tile 0 into buf0, queue order WH0, XH0a, XH0b, XH1a, XH1b, WH1
  {
    const unsigned short* sw = Wg + (size_t)srow * DF + lch * 8;
    const unsigned short* sx = Xg + (size_t)srow * DF + lch * 8;
    gld16(sw,            smem + t * 16);
    gld16(sx,            smem + 16384 + t * 16);
    gld16(sx + 64 * DF,  smem + 16384 + 8192 + t * 16);
    gld16(sx + 128 * DF, smem + 32768 + t * 16);
    gld16(sx + 192 * DF, smem + 32768 + 8192 + t * 16);
    gld16(sw + 64 * DF,  smem + 8192 + t * 16);
  }

#pragma unroll 1
  for (int kt = 0; kt < 62; kt += 2) {
    G2_TILE(kt,     0,     49152, 3, 2, 3);
    G2_TILE(kt + 1, 49152, 0,     3, 2, 3);
  }
  G2_TILE(62, 0,     49152, 3, 2, 3);
  G2_TILE(63, 49152, 0,     3, 1, 0);   // tail: drain (no stages issued)

  // epilogue: C row = d (lane>>4)*4+reg, col = token (lane&15); direct store
  float* __restrict__ P = part + (size_t)kp * N_TOK * DM;
#pragma unroll
  for (int cB = 0; cB < 2; ++cB)
#pragma unroll
    for (int ti = 0; ti < 2; ++ti) {
      const int tok = m0 + cB * 128 + wn * 32 + ti * 16 + l15;
      float* prow = P + (size_t)tok * DM + n0 + wm * 32 + kg * 4;
#pragma unroll
      for (int rA = 0; rA < 2; ++rA)
#pragma unroll
        for (int fi = 0; fi < 2; ++fi) {
          f32x4 v = acc[rA][cB][fi][ti];
          float4 o; o.x = v.x; o.y = v.y; o.z = v.z; o.w = v.w;
          *(float4*)(prow + rA * 64 + fi * 16) = o;
        }
    }
}

// ---------- reduce partials over k ----------
__global__ __launch_bounds__(256) void reduce_k(
    const float* __restrict__ part, float* __restrict__ out) {
  const size_t i = ((size_t)blockIdx.x * 256 + threadIdx.x) * 4;
  const size_t S = (size_t)N_TOK * DM;
  float4 a = *(const float4*)(part + i);
  float4 b = *(const float4*)(part + S + i);
  float4 c = *(const float4*)(part + 2 * S + i);
  float4 d = *(const float4*)(part + 3 * S + i);
  float4 r;
  r.x = a.x + b.x + c.x + d.x;
  r.y = a.y + b.y + c.y + d.y;
  r.z = a.z + b.z + c.z + d.z;
  r.w = a.w + b.w + c.w + d.w;
  *(float4*)(out + i) = r;
}

// ---------- launcher ----------
extern "C" void kernel_launch(void* const* d_in, const int* in_sizes, int n_in,
                              void* d_out, int out_size, void* d_ws, size_t ws_size,
                              hipStream_t stream) {
  const float* tokens = (const float*)d_in[0];
  const float* f1c1   = (const float*)d_in[1];
  const float* f1c2   = (const float*)d_in[2];
  const float* f2c1   = (const float*)d_in[3];
  const float* f2c2   = (const float*)d_in[4];
  const float* pb     = (const float*)d_in[5];
  const float* pw     = (const float*)d_in[6];
  float* out = (float*)d_out;

  char* ws = (char*)d_ws;
  unsigned short* xb  = (unsigned short*)(ws);                  //   4 MB
  unsigned short* w1t = (unsigned short*)(ws + (4ull  << 20));  //  32 MB (dead after gemm1)
  float*          part = (float*)(ws + (4ull << 20));           //  32 MB (reuses w1t)
  unsigned short* w2t = (unsigned short*)(ws + (36ull << 20));  //  32 MB
  unsigned short* hg  = (unsigned short*)(ws + (68ull << 20));  //  64 MB
  float*          gates = (float*)(ws + (132ull << 20));        //  32 KB

  hipLaunchKernelGGL(setup_kernel, dim3(2560), dim3(256), 0, stream,
                     tokens, pb, f1c1, f1c2, f2c1, f2c2, pw, gates, xb, w1t, w2t);
  hipLaunchKernelGGL(gemm1, dim3(8, 16, KP), dim3(512), 0, stream, xb, w1t, gates, hg);
  hipLaunchKernelGGL(gemm2, dim3(8, 8, KP), dim3(512), 0, stream, hg, w2t, part);
  hipLaunchKernelGGL(reduce_k, dim3(2048), dim3(256), 0, stream, part, out);
}

// Round 15
// 243.123 us; speedup vs baseline: 1.0932x; 1.0264x over previous
//
#include <hip/hip_runtime.h>
#include <stdint.h>

#define GAS __attribute__((address_space(1)))
#define LAS __attribute__((address_space(3)))

typedef __attribute__((ext_vector_type(8))) short short8;
typedef __attribute__((ext_vector_type(16))) float f32x16;
typedef __attribute__((ext_vector_type(4))) float f32x4;

static constexpr int N_TOK = 2048;
static constexpr int DM    = 1024;
static constexpr int DF    = 4096;
static constexpr int KP    = 4;

// ---------- helpers ----------
__device__ inline unsigned short f2bf(float f) {
  union { float f; uint32_t u; } v; v.f = f;
  uint32_t u = v.u;
  u += 0x7FFFu + ((u >> 16) & 1u);   // RNE
  return (unsigned short)(u >> 16);
}

__device__ inline uint32_t pk_bf(float lo, float hi) {
  union { float f; uint32_t u; } a, b; a.f = lo; b.f = hi;
  uint32_t ul = a.u + 0x7FFFu + ((a.u >> 16) & 1u);
  uint32_t uh = b.u + 0x7FFFu + ((b.u >> 16) & 1u);
  return (ul >> 16) | (uh & 0xFFFF0000u);
}

// gelu(v)*g, sigmoid form, overflow-safe
__device__ inline float gelu_gate(float v, float g) {
  float t0 = v * v;
  float u  = v * __builtin_fmaf(t0, -0.10294456f, -2.3022539f);
  float e  = __builtin_amdgcn_exp2f(u);
  float r  = __builtin_amdgcn_rcpf(1.0f + e);
  return v * g * r;
}

__device__ inline void gld16(const void* g, void* l) {
  __builtin_amdgcn_global_load_lds((const GAS void*)g, (LAS void*)l, 16, 0, 0);
}

// ---------- fused setup (37KB LDS -> 4 blocks/CU) ----------
// blocks [0,1024):     build_w1 (35.6KB LDS use)
// blocks [1024,2048):  build_w2, one jj per block, TWO y-half passes (36.1KB)
// blocks [2048,2560):  prep (gates + bf16 cast)
__global__ __launch_bounds__(256) void setup_kernel(
    const float* __restrict__ tokens, const float* __restrict__ pb,
    const float* __restrict__ c11, const float* __restrict__ c12,
    const float* __restrict__ c21, const float* __restrict__ c22,
    float* __restrict__ gates, unsigned short* __restrict__ xb,
    unsigned short* __restrict__ w1t, unsigned short* __restrict__ w2t) {
  __shared__ __align__(16) float sh[9248];   // 36992 B -> 4 blocks/CU
  const int blk = blockIdx.x;
  const int t = threadIdx.x;
  if (blk < 1024) {
    // ---- build_w1: w1t[k][f=x*64+y][d=a*32+b] ----
    const int k = blk >> 8, x = (blk >> 2) & 63, y0 = (blk & 3) * 16;
    float* s1  = sh;          // [a(32)][r(16)] = 512
    float* s2T = sh + 512;    // [y(16)][stride 524], idx = r*32+b  (8384)
    if (t < 128) {
      int a = t >> 2, rq = (t & 3) * 4;
      *(float4*)(s1 + a * 16 + rq) =
          *(const float4*)(c11 + (((size_t)(k * 32 + a)) * 64 + x) * 16 + rq);
    }
#pragma unroll
    for (int j = 0; j < 8; ++j) {
      int i = t + j * 256;              // [0,2048)
      int rb = i >> 2, yy0 = (i & 3) * 4;
      float4 v = *(const float4*)(c12 + (size_t)(k * 16) * 2048 + (size_t)rb * 64 + y0 + yy0);
      s2T[(yy0 + 0) * 524 + rb] = v.x;
      s2T[(yy0 + 1) * 524 + rb] = v.y;
      s2T[(yy0 + 2) * 524 + rb] = v.z;
      s2T[(yy0 + 3) * 524 + rb] = v.w;
    }
    __syncthreads();
    const int a = t >> 3, b0 = (t & 7) * 4;   // d = 4t (contiguous stores)
    float4 s1q[4];
#pragma unroll
    for (int q = 0; q < 4; ++q) s1q[q] = *(const float4*)(s1 + a * 16 + q * 4);
    const float* a0s = (const float*)s1q;
    for (int y = 0; y < 16; ++y) {
      const float* s2y = s2T + y * 524;
      float4 acc = {0.f, 0.f, 0.f, 0.f};
#pragma unroll
      for (int r = 0; r < 16; ++r) {
        float cv = a0s[r];
        float4 bv = *(const float4*)(s2y + r * 32 + b0);
        acc.x = __builtin_fmaf(cv, bv.x, acc.x);
        acc.y = __builtin_fmaf(cv, bv.y, acc.y);
        acc.z = __builtin_fmaf(cv, bv.z, acc.z);
        acc.w = __builtin_fmaf(cv, bv.w, acc.w);
      }
      ushort4 o; o.x = f2bf(acc.x); o.y = f2bf(acc.y); o.z = f2bf(acc.z); o.w = f2bf(acc.w);
      *(ushort4*)(w1t + ((size_t)k * DF + x * 64 + y0 + y) * DM + t * 4) = o;
    }
  } else if (blk < 2048) {
    // ---- build_w2: w2t[k][d=x*32+y][f=a*64+b], one jj per block,
    //      two passes of 8 y each (halved transpose buffer) ----
    const int bb = blk - 1024;
    const int jj = bb & 3;
    const int rest = bb >> 2;
    const int k = rest >> 6, x = (rest >> 1) & 31, y0 = (rest & 1) * 16;
    float* s1  = sh;           // [a(64)][r(16)] = 1024
    float* s2T = sh + 1024;    // [y(8)][stride 1028], idx = r*64+b  (8224)
    {
      int a = t >> 2, rq = (t & 3) * 4;
      *(float4*)(s1 + a * 16 + rq) =
          *(const float4*)(c21 + (((size_t)(k * 64 + a)) * 32 + x) * 16 + rq);
    }
    const int b0 = (t & 15) * 4;
    const int a = (t >> 4) + jj * 16;  // f = 4t + jj*1024
    float4 s1q[4];
#pragma unroll 1
    for (int h = 0; h < 2; ++h) {
      if (h) __syncthreads();          // protect s2T before overwrite
#pragma unroll
      for (int j = 0; j < 8; ++j) {
        int i = t + j * 256;           // [0,2048)
        int rb = i >> 1, yy0 = (i & 1) * 4;
        float4 v = *(const float4*)(c22 + (size_t)(k * 16) * 2048 + (size_t)rb * 32 + y0 + h * 8 + yy0);
        s2T[(yy0 + 0) * 1028 + rb] = v.x;
        s2T[(yy0 + 1) * 1028 + rb] = v.y;
        s2T[(yy0 + 2) * 1028 + rb] = v.z;
        s2T[(yy0 + 3) * 1028 + rb] = v.w;
      }
      __syncthreads();
      if (h == 0) {
#pragma unroll
        for (int q = 0; q < 4; ++q) s1q[q] = *(const float4*)(s1 + a * 16 + q * 4);
      }
      const float* a0s = (const float*)s1q;
      for (int yl = 0; yl < 8; ++yl) {
        const float* s2y = s2T + yl * 1028;
        float4 acc = {0.f, 0.f, 0.f, 0.f};
#pragma unroll
        for (int r = 0; r < 16; ++r) {
          float cv = a0s[r];
          float4 bv = *(const float4*)(s2y + r * 64 + b0);
          acc.x = __builtin_fmaf(cv, bv.x, acc.x);
          acc.y = __builtin_fmaf(cv, bv.y, acc.y);
          acc.z = __builtin_fmaf(cv, bv.z, acc.z);
          acc.w = __builtin_fmaf(cv, bv.w, acc.w);
        }
        ushort4 o; o.x = f2bf(acc.x); o.y = f2bf(acc.y); o.z = f2bf(acc.z); o.w = f2bf(acc.w);
        *(ushort4*)(w2t + ((size_t)k * DM + x * 32 + y0 + h * 8 + yl) * DF + t * 4 + jj * 1024) = o;
      }
    }
  } else {
    // ---- prep: gates + bf16 cast ----
    const int wave = t >> 6, lane = t & 63;
    const int n = (blk - 2048) * 4 + wave;
    float s0 = 0.f, s1v = 0.f, s2v = 0.f, s3v = 0.f;
    const float4* tr = (const float4*)(tokens + (size_t)n * DM);
#pragma unroll
    for (int j = 0; j < 4; ++j) {
      int idx = j * 64 + lane;
      float4 tv = tr[idx];
      ushort4 b;
      b.x = f2bf(tv.x); b.y = f2bf(tv.y); b.z = f2bf(tv.z); b.w = f2bf(tv.w);
      *(ushort4*)(xb + (size_t)n * DM + idx * 4) = b;
      float4 q;
      q = ((const float4*)(pb + 0 * DM))[idx]; s0  += tv.x*q.x + tv.y*q.y + tv.z*q.z + tv.w*q.w;
      q = ((const float4*)(pb + 1 * DM))[idx]; s1v += tv.x*q.x + tv.y*q.y + tv.z*q.z + tv.w*q.w;
      q = ((const float4*)(pb + 2 * DM))[idx]; s2v += tv.x*q.x + tv.y*q.y + tv.z*q.z + tv.w*q.w;
      q = ((const float4*)(pb + 3 * DM))[idx]; s3v += tv.x*q.x + tv.y*q.y + tv.z*q.z + tv.w*q.w;
    }
#pragma unroll
    for (int off = 32; off > 0; off >>= 1) {
      s0  += __shfl_xor(s0, off);
      s1v += __shfl_xor(s1v, off);
      s2v += __shfl_xor(s2v, off);
      s3v += __shfl_xor(s3v, off);
    }
    if (lane == 0) {
      float m = fmaxf(fmaxf(s0, s1v), fmaxf(s2v, s3v));
      float e0 = __expf(s0 - m), e1 = __expf(s1v - m), e2 = __expf(s2v - m), e3 = __expf(s3v - m);
      float inv = 1.0f / (e0 + e1 + e2 + e3);
      float4 g; g.x = e0 * inv; g.y = e1 * inv; g.z = e2 * inv; g.w = e3 * inv;
      *(float4*)(gates + n * 4) = g;
    }
  }
}

// ---------- shared phase-sync (counted vmcnt + raw barrier) ----------
#define PH_SYNC(V) do { \
    asm volatile("s_waitcnt vmcnt(" #V ")" ::: "memory"); \
    __builtin_amdgcn_s_barrier(); \
    __builtin_amdgcn_sched_barrier(0); \
  } while (0)

// ---------- GEMM1 (R3 best: 4-phase 256x256, counted vmcnt) ----------
// hg[k][n][f] = bf16(gelu(x@W1[k])*gate)
#define G1_TILE(KT, BO, WO, V0, V1, V2) do { \
    const int kn_ = ((KT) + 1) * 64; \
    const bool st_ = (KT) < 15; \
    /* ---- phase 0: quadrant (rA=0,cB=0); reads W0,X0; stages next W0 ---- */ \
    PH_SYNC(V0); \
    if (st_) { const unsigned short* s_ = Wg + (size_t)srow * DM + kn_ + lch * 8; \
      gld16(s_, smem + (WO) + t * 16); gld16(s_ + 64 * DM, smem + (WO) + 8192 + t * 16); } \
    _Pragma("unroll") for (int fi = 0; fi < 4; ++fi) \
      _Pragma("unroll") for (int s = 0; s < 2; ++s) \
        af[fi][s] = *(const short8*)(smem + (BO) + aRowB + fi * 2048 + (cxor16 ^ (s * 64) ^ (fi * 32))); \
    _Pragma("unroll") for (int ti = 0; ti < 2; ++ti) \
      _Pragma("unroll") for (int s = 0; s < 2; ++s) \
        bf0[ti][s] = *(const short8*)(smem + (BO) + xRowB + ti * 2048 + (cxor16 ^ (s * 64) ^ wnx64 ^ (ti * 32))); \
    __builtin_amdgcn_s_setprio(1); \
    _Pragma("unroll") for (int fi = 0; fi < 4; ++fi) \
      _Pragma("unroll") for (int ti = 0; ti < 2; ++ti) { \
        acc[0][0][fi][ti] = __builtin_amdgcn_mfma_f32_16x16x32_bf16(af[fi][0], bf0[ti][0], acc[0][0][fi][ti], 0, 0, 0); \
        acc[0][0][fi][ti] = __builtin_amdgcn_mfma_f32_16x16x32_bf16(af[fi][1], bf0[ti][1], acc[0][0][fi][ti], 0, 0, 0); } \
    __builtin_amdgcn_s_setprio(0); \
    /* ---- phase 1: quadrant (rA=0,cB=1); reads X1; stages next X0 ---- */ \
    PH_SYNC(V1); \
    if (st_) { const unsigned short* s_ = Xg + (size_t)srow * DM + kn_ + lch * 8; \
      gld16(s_, smem + (WO) + 32768 + t * 16); gld16(s_ + 64 * DM, smem + (WO) + 32768 + 8192 + t * 16); } \
    _Pragma("unroll") for (int ti = 0; ti < 2; ++ti) \
      _Pragma("unroll") for (int s = 0; s < 2; ++s) \
        bf1[ti][s] = *(const short8*)(smem + (BO) + xRowB + 16384 + ti * 2048 + (cxor16 ^ (s * 64) ^ wnx64 ^ (ti * 32))); \
    __builtin_amdgcn_s_setprio(1); \
    _Pragma("unroll") for (int fi = 0; fi < 4; ++fi) \
      _Pragma("unroll") for (int ti = 0; ti < 2; ++ti) { \
        acc[0][1][fi][ti] = __builtin_amdgcn_mfma_f32_16x16x32_bf16(af[fi][0], bf1[ti][0], acc[0][1][fi][ti], 0, 0, 0); \
        acc[0][1][fi][ti] = __builtin_amdgcn_mfma_f32_16x16x32_bf16(af[fi][1], bf1[ti][1], acc[0][1][fi][ti], 0, 0, 0); } \
    __builtin_amdgcn_s_setprio(0); \
    /* ---- phase 2: quadrant (rA=1,cB=1); reads W1; stages next X1 ---- */ \
    PH_SYNC(V2); \
    if (st_) { const unsigned short* s_ = Xg + (size_t)(128 + srow) * DM + kn_ + lch * 8; \
      gld16(s_, smem + (WO) + 32768 + 16384 + t * 16); gld16(s_ + 64 * DM, smem + (WO) + 32768 + 16384 + 8192 + t * 16); } \
    _Pragma("unroll") for (int fi = 0; fi < 4; ++fi) \
      _Pragma("unroll") for (int s = 0; s < 2; ++s) \
        af[fi][s] = *(const short8*)(smem + (BO) + aRowB + 16384 + fi * 2048 + (cxor16 ^ (s * 64) ^ (fi * 32))); \
    __builtin_amdgcn_s_setprio(1); \
    _Pragma("unroll") for (int fi = 0; fi < 4; ++fi) \
      _Pragma("unroll") for (int ti = 0; ti < 2; ++ti) { \
        acc[1][1][fi][ti] = __builtin_amdgcn_mfma_f32_16x16x32_bf16(af[fi][0], bf1[ti][0], acc[1][1][fi][ti], 0, 0, 0); \
        acc[1][1][fi][ti] = __builtin_amdgcn_mfma_f32_16x16x32_bf16(af[fi][1], bf1[ti][1], acc[1][1][fi][ti], 0, 0, 0); } \
    __builtin_amdgcn_s_setprio(0); \
    /* ---- phase 3: quadrant (rA=1,cB=0); no new reads; stages next W1 ---- */ \
    if (st_) { const unsigned short* s_ = Wg + (size_t)(128 + srow) * DM + kn_ + lch * 8; \
      gld16(s_, smem + (WO) + 16384 + t * 16); gld16(s_ + 64 * DM, smem + (WO) + 16384 + 8192 + t * 16); } \
    __builtin_amdgcn_s_setprio(1); \
    _Pragma("unroll") for (int fi = 0; fi < 4; ++fi) \
      _Pragma("unroll") for (int ti = 0; ti < 2; ++ti) { \
        acc[1][0][fi][ti] = __builtin_amdgcn_mfma_f32_16x16x32_bf16(af[fi][0], bf0[ti][0], acc[1][0][fi][ti], 0, 0, 0); \
        acc[1][0][fi][ti] = __builtin_amdgcn_mfma_f32_16x16x32_bf16(af[fi][1], bf0[ti][1], acc[1][0][fi][ti], 0, 0, 0); } \
    __builtin_amdgcn_s_setprio(0); \
  } while (0)

__global__ __launch_bounds__(512, 1) void gemm1(
    const unsigned short* __restrict__ xb, const unsigned short* __restrict__ w1t,
    const float* __restrict__ gates, unsigned short* __restrict__ hg) {
  __shared__ __align__(16) char smem[131072];
  const int t = threadIdx.x, lane = t & 63, wv = t >> 6;
  const int wm = wv >> 2, wn = wv & 3;
  // T1 XCD swizzle (bijective, nwg=512)
  const int hw = blockIdx.x + (blockIdx.y << 3) + (blockIdx.z << 7);
  const int lg = (hw & 7) * 64 + (hw >> 3);
  const int m0 = (lg & 7) * 256;          // token tile
  const int f0 = ((lg >> 3) & 15) * 256;  // f tile
  const int kp = lg >> 7;
  const unsigned short* __restrict__ Wg = w1t + (size_t)kp * DF * DM + (size_t)f0 * DM;
  const unsigned short* __restrict__ Xg = xb + (size_t)m0 * DM;

  const int srow = t >> 3;
  const int lch  = (t & 7) ^ (srow & 7) ^ (srow >> 3);
  const int l15 = lane & 15, kg = lane >> 4;
  const int cxor16 = (kg ^ (lane & 7) ^ (l15 >> 3)) * 16;  // bytes
  const int wnx64  = (wn & 1) * 64;
  const int aRowB  = (wm * 64 + l15) * 128;                // W rows, + rA*16384 + fi*2048
  const int xRowB  = 32768 + (wn * 32 + l15) * 128;        // X rows, + cB*16384 + ti*2048

  f32x4 acc[2][2][4][2] = {};        // [rA][cB][fi][ti]
  short8 af[4][2], bf0[2][2], bf1[2][2];

  // prologue: stage tile 0 (queue order W0, X0, X1, W1)
  {
    const unsigned short* sw = Wg + (size_t)srow * DM + lch * 8;
    const unsigned short* sx = Xg + (size_t)srow * DM + lch * 8;
    gld16(sw,            smem + t * 16);
    gld16(sw + 64 * DM,  smem + 8192 + t * 16);
    gld16(sx,            smem + 32768 + t * 16);
    gld16(sx + 64 * DM,  smem + 32768 + 8192 + t * 16);
    gld16(sx + 128 * DM, smem + 32768 + 16384 + t * 16);
    gld16(sx + 192 * DM, smem + 32768 + 16384 + 8192 + t * 16);
    gld16(sw + 128 * DM, smem + 16384 + t * 16);
    gld16(sw + 192 * DM, smem + 16384 + 8192 + t * 16);
  }

#pragma unroll 1
  for (int kt = 0; kt < 14; kt += 2) {
    G1_TILE(kt,     0,     65536, 4, 4, 4);
    G1_TILE(kt + 1, 65536, 0,     4, 4, 4);
  }
  G1_TILE(14, 0,     65536, 4, 4, 4);
  G1_TILE(15, 65536, 0,     4, 2, 0);   // tail: drain (no stages issued)

  // epilogue: C row = f (lane>>4)*4+reg, col = token (lane&15)
  unsigned short* __restrict__ H = hg + (size_t)kp * N_TOK * DF;
#pragma unroll
  for (int cB = 0; cB < 2; ++cB)
#pragma unroll
    for (int ti = 0; ti < 2; ++ti) {
      const int tok = m0 + cB * 128 + wn * 32 + ti * 16 + l15;
      const float g = gates[tok * 4 + kp];
      unsigned short* hrow = H + (size_t)tok * DF + f0 + wm * 64 + kg * 4;
#pragma unroll
      for (int rA = 0; rA < 2; ++rA)
#pragma unroll
        for (int fi = 0; fi < 4; ++fi) {
          f32x4 v = acc[rA][cB][fi][ti];
          float r0 = gelu_gate(v.x, g);
          float r1 = gelu_gate(v.y, g);
          float r2 = gelu_gate(v.z, g);
          float r3 = gelu_gate(v.w, g);
          uint2 p; p.x = pk_bf(r0, r1); p.y = pk_bf(r2, r3);
          *(uint2*)(hrow + rA * 128 + fi * 16) = p;
        }
    }
}

// ---------- GEMM2 (R3 best: counted-vmcnt 4-phase, 256tok x 128d) ----------
// part[k][n][d] = (1+pw[k,d]) * (hg[k]@W2[k])[n,d]
#define G2_TILE(KT, BO, WO, V0, V1, V2) do { \
    const int kn_ = ((KT) + 1) * 64; \
    const bool st_ = (KT) < 63; \
    /* ---- phase 0: (rA=0,cB=0); reads WH0,XH0; stages next WH0 ---- */ \
    PH_SYNC(V0); \
    if (st_) gld16(Wg + (size_t)srow * DF + kn_ + lch * 8, smem + (WO) + t * 16); \
    _Pragma("unroll") for (int fi = 0; fi < 2; ++fi) \
      _Pragma("unroll") for (int s = 0; s < 2; ++s) \
        af[fi][s] = *(const short8*)(smem + (BO) + awRowB + fi * 2048 + (cxor16 ^ awx ^ (fi * 32) ^ (s * 64))); \
    _Pragma("unroll") for (int ti = 0; ti < 2; ++ti) \
      _Pragma("unroll") for (int s = 0; s < 2; ++s) \
        bf0[ti][s] = *(const short8*)(smem + (BO) + xRowB + ti * 2048 + (cxor16 ^ wnx64 ^ (ti * 32) ^ (s * 64))); \
    __builtin_amdgcn_s_setprio(1); \
    _Pragma("unroll") for (int fi = 0; fi < 2; ++fi) \
      _Pragma("unroll") for (int ti = 0; ti < 2; ++ti) { \
        acc[0][0][fi][ti] = __builtin_amdgcn_mfma_f32_16x16x32_bf16(af[fi][0], bf0[ti][0], acc[0][0][fi][ti], 0, 0, 0); \
        acc[0][0][fi][ti] = __builtin_amdgcn_mfma_f32_16x16x32_bf16(af[fi][1], bf0[ti][1], acc[0][0][fi][ti], 0, 0, 0); } \
    __builtin_amdgcn_s_setprio(0); \
    /* ---- phase 1: (rA=0,cB=1); reads XH1; stages next XH0 ---- */ \
    PH_SYNC(V1); \
    if (st_) { const unsigned short* s_ = Xg + (size_t)srow * DF + kn_ + lch * 8; \
      gld16(s_, smem + (WO) + 16384 + t * 16); gld16(s_ + 64 * DF, smem + (WO) + 16384 + 8192 + t * 16); } \
    _Pragma("unroll") for (int ti = 0; ti < 2; ++ti) \
      _Pragma("unroll") for (int s = 0; s < 2; ++s) \
        bf1[ti][s] = *(const short8*)(smem + (BO) + xRowB + 16384 + ti * 2048 + (cxor16 ^ wnx64 ^ (ti * 32) ^ (s * 64))); \
    __builtin_amdgcn_s_setprio(1); \
    _Pragma("unroll") for (int fi = 0; fi < 2; ++fi) \
      _Pragma("unroll") for (int ti = 0; ti < 2; ++ti) { \
        acc[0][1][fi][ti] = __builtin_amdgcn_mfma_f32_16x16x32_bf16(af[fi][0], bf1[ti][0], acc[0][1][fi][ti], 0, 0, 0); \
        acc[0][1][fi][ti] = __builtin_amdgcn_mfma_f32_16x16x32_bf16(af[fi][1], bf1[ti][1], acc[0][1][fi][ti], 0, 0, 0); } \
    __builtin_amdgcn_s_setprio(0); \
    /* ---- phase 2: (rA=1,cB=1); reads WH1; stages next XH1 ---- */ \
    PH_SYNC(V2); \
    if (st_) { const unsigned short* s_ = Xg + (size_t)(128 + srow) * DF + kn_ + lch * 8; \
      gld16(s_, smem + (WO) + 32768 + t * 16); gld16(s_ + 64 * DF, smem + (WO) + 32768 + 8192 + t * 16); } \
    _Pragma("unroll") for (int fi = 0; fi < 2; ++fi) \
      _Pragma("unroll") for (int s = 0; s < 2; ++s) \
        af[fi][s] = *(const short8*)(smem + (BO) + awRowB + 8192 + fi * 2048 + (cxor16 ^ awx ^ (fi * 32) ^ (s * 64))); \
    __builtin_amdgcn_s_setprio(1); \
    _Pragma("unroll") for (int fi = 0; fi < 2; ++fi) \
      _Pragma("unroll") for (int ti = 0; ti < 2; ++ti) { \
        acc[1][1][fi][ti] = __builtin_amdgcn_mfma_f32_16x16x32_bf16(af[fi][0], bf1[ti][0], acc[1][1][fi][ti], 0, 0, 0); \
        acc[1][1][fi][ti] = __builtin_amdgcn_mfma_f32_16x16x32_bf16(af[fi][1], bf1[ti][1], acc[1][1][fi][ti], 0, 0, 0); } \
    __builtin_amdgcn_s_setprio(0); \
    /* ---- phase 3: (rA=1,cB=0); register-only; stages next WH1 ---- */ \
    if (st_) gld16(Wg + (size_t)(64 + srow) * DF + kn_ + lch * 8, smem + (WO) + 8192 + t * 16); \
    __builtin_amdgcn_s_setprio(1); \
    _Pragma("unroll") for (int fi = 0; fi < 2; ++fi) \
      _Pragma("unroll") for (int ti = 0; ti < 2; ++ti) { \
        acc[1][0][fi][ti] = __builtin_amdgcn_mfma_f32_16x16x32_bf16(af[fi][0], bf0[ti][0], acc[1][0][fi][ti], 0, 0, 0); \
        acc[1][0][fi][ti] = __builtin_amdgcn_mfma_f32_16x16x32_bf16(af[fi][1], bf0[ti][1], acc[1][0][fi][ti], 0, 0, 0); } \
    __builtin_amdgcn_s_setprio(0); \
  } while (0)

__global__ __launch_bounds__(512, 1) void gemm2(
    const unsigned short* __restrict__ hg, const unsigned short* __restrict__ w2t,
    const float* __restrict__ pw, float* __restrict__ part) {
  __shared__ __align__(16) char smem[98304];
  const int t = threadIdx.x, lane = t & 63, wv = t >> 6;
  const int wm = wv >> 2, wn = wv & 3;
  // T1 XCD swizzle (bijective, nwg=256)
  const int hw = blockIdx.x + (blockIdx.y << 3) + (blockIdx.z << 6);
  const int lg = (hw & 7) * 32 + (hw >> 3);
  const int m0 = (lg & 7) * 256;         // token tile
  const int n0 = ((lg >> 3) & 7) * 128;  // d tile
  const int kp = lg >> 6;
  const unsigned short* __restrict__ Wg = w2t + (size_t)kp * DM * DF + (size_t)n0 * DF;
  const unsigned short* __restrict__ Xg = hg + (size_t)kp * N_TOK * DF + (size_t)m0 * DF;

  const int srow = t >> 3;
  const int lch  = (t & 7) ^ (srow & 7) ^ (srow >> 3);
  const int l15 = lane & 15, kg = lane >> 4;
  const int cxor16 = (kg ^ (lane & 7) ^ (l15 >> 3)) * 16;  // bytes
  const int wnx64  = (wn & 1) * 64;
  const int awx    = wm * 64;                               // (wm*4)*16 bytes
  const int awRowB = (wm * 32 + l15) * 128;                 // W rows, + rA*8192 + fi*2048
  const int xRowB  = 16384 + (wn * 32 + l15) * 128;         // X rows, + cB*16384 + ti*2048

  f32x4 acc[2][2][2][2] = {};        // [rA][cB][fi][ti]
  short8 af[2][2], bf0[2][2], bf1[2][2];

  // prologue: stage tile 0 into buf0, queue order WH0, XH0a, XH0b, XH1a, XH1b, WH1
  {
    const unsigned short* sw = Wg + (size_t)srow * DF + lch * 8;
    const unsigned short* sx = Xg + (size_t)srow * DF + lch * 8;
    gld16(sw,            smem + t * 16);
    gld16(sx,            smem + 16384 + t * 16);
    gld16(sx + 64 * DF,  smem + 16384 + 8192 + t * 16);
    gld16(sx + 128 * DF, smem + 32768 + t * 16);
    gld16(sx + 192 * DF, smem + 32768 + 8192 + t * 16);
    gld16(sw + 64 * DF,  smem + 8192 + t * 16);
  }

#pragma unroll 1
  for (int kt = 0; kt < 62; kt += 2) {
    G2_TILE(kt,     0,     49152, 3, 2, 3);
    G2_TILE(kt + 1, 49152, 0,     3, 2, 3);
  }
  G2_TILE(62, 0,     49152, 3, 2, 3);
  G2_TILE(63, 49152, 0,     3, 1, 0);   // tail: drain (no stages issued)

  // epilogue: C row = d (lane>>4)*4+reg, col = token (lane&15); scale by (1+pw)
  float* __restrict__ P = part + (size_t)kp * N_TOK * DM;
  float4 pwv[2][2];   // [rA][fi]
#pragma unroll
  for (int rA = 0; rA < 2; ++rA)
#pragma unroll
    for (int fi = 0; fi < 2; ++fi) {
      float4 w = *(const float4*)(pw + kp * DM + n0 + rA * 64 + wm * 32 + fi * 16 + kg * 4);
      pwv[rA][fi].x = 1.0f + w.x; pwv[rA][fi].y = 1.0f + w.y;
      pwv[rA][fi].z = 1.0f + w.z; pwv[rA][fi].w = 1.0f + w.w;
    }
#pragma unroll
  for (int cB = 0; cB < 2; ++cB)
#pragma unroll
    for (int ti = 0; ti < 2; ++ti) {
      const int tok = m0 + cB * 128 + wn * 32 + ti * 16 + l15;
      float* prow = P + (size_t)tok * DM + n0 + wm * 32 + kg * 4;
#pragma unroll
      for (int rA = 0; rA < 2; ++rA)
#pragma unroll
        for (int fi = 0; fi < 2; ++fi) {
          f32x4 v = acc[rA][cB][fi][ti];
          float4 o;
          o.x = pwv[rA][fi].x * v.x;
          o.y = pwv[rA][fi].y * v.y;
          o.z = pwv[rA][fi].z * v.z;
          o.w = pwv[rA][fi].w * v.w;
          *(float4*)(prow + rA * 64 + fi * 16) = o;
        }
    }
}

// ---------- reduce partials over k ----------
__global__ __launch_bounds__(256) void reduce_k(
    const float* __restrict__ part, float* __restrict__ out) {
  const size_t i = ((size_t)blockIdx.x * 256 + threadIdx.x) * 4;
  const size_t S = (size_t)N_TOK * DM;
  float4 a = *(const float4*)(part + i);
  float4 b = *(const float4*)(part + S + i);
  float4 c = *(const float4*)(part + 2 * S + i);
  float4 d = *(const float4*)(part + 3 * S + i);
  float4 r;
  r.x = a.x + b.x + c.x + d.x;
  r.y = a.y + b.y + c.y + d.y;
  r.z = a.z + b.z + c.z + d.z;
  r.w = a.w + b.w + c.w + d.w;
  *(float4*)(out + i) = r;
}

// ---------- launcher ----------
extern "C" void kernel_launch(void* const* d_in, const int* in_sizes, int n_in,
                              void* d_out, int out_size, void* d_ws, size_t ws_size,
                              hipStream_t stream) {
  const float* tokens = (const float*)d_in[0];
  const float* f1c1   = (const float*)d_in[1];
  const float* f1c2   = (const float*)d_in[2];
  const float* f2c1   = (const float*)d_in[3];
  const float* f2c2   = (const float*)d_in[4];
  const float* pb     = (const float*)d_in[5];
  const float* pw     = (const float*)d_in[6];
  float* out = (float*)d_out;

  char* ws = (char*)d_ws;
  unsigned short* xb  = (unsigned short*)(ws);                  //   4 MB
  unsigned short* w1t = (unsigned short*)(ws + (4ull  << 20));  //  32 MB (dead after gemm1)
  float*          part = (float*)(ws + (4ull << 20));           //  32 MB (reuses w1t)
  unsigned short* w2t = (unsigned short*)(ws + (36ull << 20));  //  32 MB
  unsigned short* hg  = (unsigned short*)(ws + (68ull << 20));  //  64 MB
  float*          gates = (float*)(ws + (132ull << 20));        //  32 KB

  hipLaunchKernelGGL(setup_kernel, dim3(2560), dim3(256), 0, stream,
                     tokens, pb, f1c1, f1c2, f2c1, f2c2, gates, xb, w1t, w2t);
  hipLaunchKernelGGL(gemm1, dim3(8, 16, KP), dim3(512), 0, stream, xb, w1t, gates, hg);
  hipLaunchKernelGGL(gemm2, dim3(8, 8, KP), dim3(512), 0, stream, hg, w2t, pw, part);
  hipLaunchKernelGGL(reduce_k, dim3(2048), dim3(256), 0, stream, part, out);
}